// Round 7
// baseline (368.408 us; speedup 1.0000x reference)
//
#include <hip/hip_runtime.h>
#include <hip/hip_bf16.h>

typedef __attribute__((ext_vector_type(8))) short short8;
typedef __attribute__((ext_vector_type(4))) float f32x4;

#define D 256
#define MT 32             // nodes per tile
#define NW 8              // waves per block (512 threads)
#define GRID_MAIN 512     // 2 blocks per CU
#define G 16

#define BAR_LGKM asm volatile("s_waitcnt lgkmcnt(0)\ns_barrier" ::: "memory")

__device__ __forceinline__ unsigned pack2(float a, float b) {
    __hip_bfloat162 h = __float22bfloat162_rn(make_float2(a, b));
    return *(unsigned*)&h;
}
__device__ __forceinline__ float bflo(unsigned v) { return __uint_as_float(v << 16); }
__device__ __forceinline__ float bfhi(unsigned v) { return __uint_as_float(v & 0xffff0000u); }
__device__ __forceinline__ float fast_sigmoid(float x) {
    return __builtin_amdgcn_rcpf(1.f + __expf(-x));
}
__device__ __forceinline__ void dma16(const void* g, void* l) {
    __builtin_amdgcn_global_load_lds((const __attribute__((address_space(1))) unsigned int*)g,
                                     (__attribute__((address_space(3))) unsigned int*)l, 16, 0, 0);
}
__device__ __forceinline__ void dma4(const void* g, void* l) {
    __builtin_amdgcn_global_load_lds((const __attribute__((address_space(1))) unsigned int*)g,
                                     (__attribute__((address_space(3))) unsigned int*)l, 4, 0, 0);
}

// K0: W_u fp32 -> bf16 row-major (RTNE)
__global__ void k_convert(const float* __restrict__ W, unsigned short* __restrict__ Wb, int n) {
    int i = blockIdx.x * 256 + threadIdx.x;
    if (i < n) Wb[i] = (unsigned short)(pack2(W[i], 0.f) & 0xffffu);
}

// K1: feat_v[b] = feat[last_nodes[b]] @ W_v.T + b_v
__global__ __launch_bounds__(256) void k_featv(
    const float* __restrict__ feat, const int* __restrict__ last_nodes,
    const float* __restrict__ Wv, const float* __restrict__ bv,
    float* __restrict__ featv, int Bseg) {
    __shared__ float fln[G][D];
    const int t  = threadIdx.x;
    const int b0 = blockIdx.x * G;
    for (int g = 0; g < G; ++g) {
        int b = b0 + g;
        int ln = (b < Bseg) ? last_nodes[b] : 0;
        fln[g][t] = feat[(long)ln * D + t];
    }
    __syncthreads();
    float acc[G];
    float bvj = bv[t];
    #pragma unroll
    for (int g = 0; g < G; ++g) acc[g] = bvj;
    const float* wr = Wv + (long)t * D;
    for (int k = 0; k < D; k += 4) {
        float4 w4 = *(const float4*)(wr + k);
        #pragma unroll
        for (int g = 0; g < G; ++g) {
            acc[g] += w4.x * fln[g][k]     + w4.y * fln[g][k + 1]
                    + w4.z * fln[g][k + 2] + w4.w * fln[g][k + 3];
        }
    }
    for (int g = 0; g < G; ++g)
        if (b0 + g < Bseg) featv[(long)(b0 + g) * D + t] = acc[g];
}

// K2: persistent fused kernel. DMA-staged fp32 -> convert -> swizzled bf16 tile.
// MT=32, 2 blocks/CU, register-carried segment sum.
// bf16 row r (512B): logical 16B-granule g stored at physical granule g ^ (r&7).
__global__ __launch_bounds__(512, 4) void k_main(
    const float* __restrict__ feat, const float* __restrict__ cnt,
    const int* __restrict__ seg, const unsigned short* __restrict__ Wub,
    const float* __restrict__ featv, const float* __restrict__ we,
    float* __restrict__ rst, int N) {

    __shared__ float stage[MT][D];                 // 32 KB, linear (DMA dest)
    __shared__ unsigned short Abuf[2][MT][D];      // 32 KB, swizzled bf16
    __shared__ int   seg_s[2][64];
    __shared__ float cnt_s[2][64];
    __shared__ float e_s[NW][MT];
    __shared__ float alpha_s[MT];

    const int t  = threadIdx.x;
    const int w  = t >> 6;
    const int l  = t & 63;
    const int rl = l & 15;
    const int h  = l >> 4;

    const int T   = (N + MT - 1) / MT;
    const int nb  = gridDim.x;
    const int per = T / nb, rem = T % nb;
    const int bid = blockIdx.x;
    const int c0  = bid * per + (bid < rem ? bid : rem);
    const int c1  = c0 + per + (bid < rem ? 1 : 0);
    if (c0 >= c1) return;

    // w_e fragment: lane's j = 32w + 16mt + 4h + r
    f32x4 wev[2];
    wev[0] = *(const f32x4*)(we + 32 * w + h * 4);
    wev[1] = *(const f32x4*)(we + 32 * w + 16 + h * 4);

    // ---- prologue: DMA tile c0 -> stage, convert -> Abuf[0] ----
    {
        const long m0 = (long)c0 * MT;
        #pragma unroll
        for (int i = 0; i < 4; ++i) {
            int r = w + 8 * i;
            long n = m0 + r; if (n > (long)N - 1) n = (long)N - 1;
            dma16(feat + n * D + 4 * l, &stage[r][0]);
        }
        if (w == 0) {
            long idx = m0 + l; if (idx > (long)N - 1) idx = (long)N - 1;
            dma4(seg + idx, &seg_s[0][0]);
            dma4(cnt + idx, &cnt_s[0][0]);
        }
        asm volatile("s_waitcnt vmcnt(0)" ::: "memory");
        #pragma unroll
        for (int i = 0; i < 4; ++i) {
            int r = w + 8 * i;
            f32x4 fv = *(const f32x4*)&stage[r][4 * l];
            *(uint2*)&Abuf[0][r][((((l >> 1) ^ (r & 7))) << 3) + ((l & 1) << 2)] =
                make_uint2(pack2(fv[0], fv[1]), pack2(fv[2], fv[3]));
        }
        BAR_LGKM;
    }

    // register-carried segment-sum state (threads 0..127, dims {2t, 2t+1})
    float ca = 0.f, cb = 0.f;
    int cseg = seg_s[0][0];

    int cur = 0;
    for (int tt = c0; tt < c1; ++tt, cur ^= 1) {
        const int n0   = tt * MT;
        const bool more = (tt + 1 < c1);

        // 1. DMA tile t+1 -> stage (+ seg/cnt -> [cur^1])
        if (more) {
            const long m1 = (long)(tt + 1) * MT;
            #pragma unroll
            for (int i = 0; i < 4; ++i) {
                int r = w + 8 * i;
                long n = m1 + r; if (n > (long)N - 1) n = (long)N - 1;
                dma16(feat + n * D + 4 * l, &stage[r][0]);
            }
            if (w == 0) {
                long idx = m1 + l; if (idx > (long)N - 1) idx = (long)N - 1;
                dma4(seg + idx, &seg_s[cur ^ 1][0]);
                dma4(cnt + idx, &cnt_s[cur ^ 1][0]);
            }
        }
        asm volatile("" ::: "memory");

        // 2. segment ids + featv (L2)
        int sgv[2];
        #pragma unroll
        for (int nt = 0; nt < 2; ++nt) sgv[nt] = seg_s[cur][nt * 16 + rl];
        f32x4 fvr[2][2];
        #pragma unroll
        for (int nt = 0; nt < 2; ++nt) {
            const float* fb = featv + (long)sgv[nt] * D + 32 * w + h * 4;
            fvr[0][nt] = *(const f32x4*)(fb);
            fvr[1][nt] = *(const f32x4*)(fb + 16);
        }

        // 3. MFMA: u[j][node]; A streamed from L2, B from swizzled bf16 LDS
        f32x4 acc[2][2];
        #pragma unroll
        for (int mt = 0; mt < 2; ++mt)
            #pragma unroll
            for (int nt = 0; nt < 2; ++nt) acc[mt][nt] = (f32x4)0.f;

        const unsigned short* Ab = &Abuf[cur][0][0];
        const unsigned short* abase = Wub + (long)(32 * w + rl) * D + h * 8;
        __builtin_amdgcn_s_setprio(1);
        #pragma unroll
        for (int s = 0; s < 8; ++s) {
            short8 av[2], bfr[2];
            av[0] = *(const short8*)(abase + s * 32);
            av[1] = *(const short8*)(abase + (long)16 * D + s * 32);
            #pragma unroll
            for (int nt = 0; nt < 2; ++nt) {
                int R  = nt * 16 + rl;
                int gr = (s * 4 + h) ^ (rl & 7);
                bfr[nt] = *(const short8*)(Ab + R * D + gr * 8);
            }
            #pragma unroll
            for (int mt = 0; mt < 2; ++mt)
                #pragma unroll
                for (int nt = 0; nt < 2; ++nt)
                    acc[mt][nt] = __builtin_amdgcn_mfma_f32_16x16x32_bf16(av[mt], bfr[nt], acc[mt][nt], 0, 0, 0);
        }
        __builtin_amdgcn_s_setprio(0);

        // 4. epilogue: e partials; j = 32w + 16mt + 4h + r, node = 16nt + rl
        float ep[2] = {0.f, 0.f};
        #pragma unroll
        for (int mt = 0; mt < 2; ++mt)
            #pragma unroll
            for (int nt = 0; nt < 2; ++nt)
                #pragma unroll
                for (int r = 0; r < 4; ++r)
                    ep[nt] += wev[mt][r] * fast_sigmoid(acc[mt][nt][r] + fvr[mt][nt][r]);
        #pragma unroll
        for (int nt = 0; nt < 2; ++nt) {
            ep[nt] += __shfl_xor(ep[nt], 16);
            ep[nt] += __shfl_xor(ep[nt], 32);
        }
        if (h == 0) {
            #pragma unroll
            for (int nt = 0; nt < 2; ++nt) e_s[w][nt * 16 + rl] = ep[nt];
        }
        BAR_LGKM;                                   // barrier 1

        // 5. alpha (zero for OOB rows)
        if (t < MT) {
            float e = 0.f;
            #pragma unroll
            for (int q = 0; q < NW; ++q) e += e_s[q][t];
            alpha_s[t] = (n0 + t < N) ? e * cnt_s[cur][t] : 0.f;
        }
        BAR_LGKM;                                   // barrier 2

        // 6. wait own DMA, convert stage -> Abuf[cur^1] (rows this wave DMA'd)
        if (more) {
            asm volatile("s_waitcnt vmcnt(0)" ::: "memory");
            #pragma unroll
            for (int i = 0; i < 4; ++i) {
                int r = w + 8 * i;
                f32x4 fv = *(const f32x4*)&stage[r][4 * l];
                *(uint2*)&Abuf[cur ^ 1][r][((((l >> 1) ^ (r & 7))) << 3) + ((l & 1) << 2)] =
                    make_uint2(pack2(fv[0], fv[1]), pack2(fv[2], fv[3]));
            }
        }

        // 7. P4: register-carried segment sum; thread p<128 owns dims {2p, 2p+1}
        if (t < 128) {
            const int p   = t;
            const int gl0 = p >> 2;
            const int off = p & 3;
            const unsigned* Ab32 = (const unsigned*)Ab;
            const int* st = seg_s[cur];
            int s0 = st[0], s31 = st[MT - 1];
            if (s0 == s31 && s0 == cseg) {
                float p0 = 0.f, p1 = 0.f, q0 = 0.f, q1 = 0.f;
                #pragma unroll
                for (int i = 0; i < MT; i += 2) {
                    unsigned v0 = Ab32[(i + 0) * 128 + ((gl0 ^ ((i + 0) & 7)) << 2) + off];
                    unsigned v1 = Ab32[(i + 1) * 128 + ((gl0 ^ ((i + 1) & 7)) << 2) + off];
                    float a0 = alpha_s[i + 0], a1 = alpha_s[i + 1];
                    p0 += bflo(v0) * a0; q0 += bfhi(v0) * a0;
                    p1 += bflo(v1) * a1; q1 += bfhi(v1) * a1;
                }
                ca += p0 + p1; cb += q0 + q1;
            } else {
                for (int i = 0; i < MT; ++i) {
                    int sgi = st[i];                        // wave-uniform
                    if (sgi != cseg) {
                        long rb = (long)cseg * D + 2 * p;
                        atomicAdd(&rst[rb], ca); atomicAdd(&rst[rb + 1], cb);
                        ca = cb = 0.f; cseg = sgi;
                    }
                    unsigned v = Ab32[i * 128 + ((gl0 ^ (i & 7)) << 2) + off];
                    float al = alpha_s[i];
                    ca += bflo(v) * al; cb += bfhi(v) * al;
                }
            }
        }
        BAR_LGKM;                                   // barrier 3
    }

    // final flush of carried partials
    if (t < 128) {
        long rb = (long)cseg * D + 2 * t;
        atomicAdd(&rst[rb], ca); atomicAdd(&rst[rb + 1], cb);
    }
}

extern "C" void kernel_launch(void* const* d_in, const int* in_sizes, int n_in,
                              void* d_out, int out_size, void* d_ws, size_t ws_size,
                              hipStream_t stream) {
    const float* feat = (const float*)d_in[0];
    const float* cnt  = (const float*)d_in[1];
    const int*   segp = (const int*)d_in[2];
    const int*   last = (const int*)d_in[3];
    const float* Wu   = (const float*)d_in[4];
    const float* Wv   = (const float*)d_in[5];
    const float* bv   = (const float*)d_in[6];
    const float* we   = (const float*)d_in[7];
    float* rst = (float*)d_out;

    const int N    = in_sizes[1];
    const int Bseg = in_sizes[3];

    unsigned short* Wub   = (unsigned short*)d_ws;
    float*          featv = (float*)((char*)d_ws + (size_t)D * D * sizeof(unsigned short));

    hipMemsetAsync(d_out, 0, (size_t)out_size * sizeof(float), stream);
    k_convert<<<(D * D + 255) / 256, 256, 0, stream>>>(Wu, Wub, D * D);
    k_featv<<<(Bseg + G - 1) / G, 256, 0, stream>>>(feat, last, Wv, bv, featv, Bseg);
    k_main<<<GRID_MAIN, 512, 0, stream>>>(feat, cnt, segp, Wub, featv, we, rst, N);
}

// Round 8
// 199.405 us; speedup vs baseline: 1.8475x; 1.8475x over previous
//
#include <hip/hip_runtime.h>
#include <hip/hip_bf16.h>

typedef __attribute__((ext_vector_type(8))) short short8;
typedef __attribute__((ext_vector_type(4))) float f32x4;

#define D 256
#define MT 64
#define NW 8              // waves per block (512 threads)
#define GRID_MAIN 512     // 2 blocks per CU (VGPR 128, LDS 67.5 KB -> both fit)
#define G 16

__device__ __forceinline__ unsigned pack2(float a, float b) {
    __hip_bfloat162 h = __float22bfloat162_rn(make_float2(a, b));
    return *(unsigned*)&h;
}
__device__ __forceinline__ float fast_sigmoid(float x) {
    return __builtin_amdgcn_rcpf(1.f + __expf(-x));
}

// K0: fused prep — blocks [0,256): W_u fp32->bf16; blocks [256,...): zero rst
__global__ __launch_bounds__(256) void k_prep(
    const float* __restrict__ W, unsigned short* __restrict__ Wb,
    float* __restrict__ rst, int nW, int nOut) {
    int b = blockIdx.x;
    if (b < 256) {
        int i = b * 256 + threadIdx.x;
        if (i < nW) Wb[i] = (unsigned short)(pack2(W[i], 0.f) & 0xffffu);
    } else {
        int i = (b - 256) * 256 + threadIdx.x;
        if (i < nOut) rst[i] = 0.f;
    }
}

// K1: feat_v[b] = feat[last_nodes[b]] @ W_v.T + b_v
__global__ __launch_bounds__(256) void k_featv(
    const float* __restrict__ feat, const int* __restrict__ last_nodes,
    const float* __restrict__ Wv, const float* __restrict__ bv,
    float* __restrict__ featv, int Bseg) {
    __shared__ float fln[G][D];
    const int t  = threadIdx.x;
    const int b0 = blockIdx.x * G;
    for (int g = 0; g < G; ++g) {
        int b = b0 + g;
        int ln = (b < Bseg) ? last_nodes[b] : 0;
        fln[g][t] = feat[(long)ln * D + t];
    }
    __syncthreads();
    float acc[G];
    float bvj = bv[t];
    #pragma unroll
    for (int g = 0; g < G; ++g) acc[g] = bvj;
    const float* wr = Wv + (long)t * D;
    for (int k = 0; k < D; k += 4) {
        float4 w4 = *(const float4*)(wr + k);
        #pragma unroll
        for (int g = 0; g < G; ++g) {
            acc[g] += w4.x * fln[g][k]     + w4.y * fln[g][k + 1]
                    + w4.z * fln[g][k + 2] + w4.w * fln[g][k + 3];
        }
    }
    for (int g = 0; g < G; ++g)
        if (b0 + g < Bseg) featv[(long)(b0 + g) * D + t] = acc[g];
}

// K2: persistent fused kernel (round-4 structure), bf16 XOR-swizzled LDS tile,
// reg-staged, double-buffered, W_u reg-resident, now 2 blocks/CU via grid=512.
// LDS layout: tile row r (512 B), 16B-granule g stored at granule (g ^ (r&7)).
__global__ __launch_bounds__(512, 2) void k_main(
    const float* __restrict__ feat, const float* __restrict__ cnt,
    const int* __restrict__ seg, const unsigned short* __restrict__ Wub,
    const float* __restrict__ featv, const float* __restrict__ we,
    float* __restrict__ rst, int N) {

    __shared__ unsigned short Abuf[2][MT][D];   // 64 KB
    __shared__ float e_s[NW][MT];               // 2 KB
    __shared__ int   seg_s[2][MT];
    __shared__ float cnt_s[2][MT];
    __shared__ float alpha_s[MT];

    const int t  = threadIdx.x;
    const int w  = t >> 6;
    const int l  = t & 63;
    const int rl = l & 15;
    const int h  = l >> 4;

    const int T   = (N + MT - 1) / MT;
    const int nb  = gridDim.x;
    const int per = T / nb, rem = T % nb;
    const int bid = blockIdx.x;
    const int c0  = bid * per + (bid < rem ? bid : rem);
    const int c1  = c0 + per + (bid < rem ? 1 : 0);
    if (c0 >= c1) return;

    // W_u rows [32w, 32w+32) resident in registers
    short8 a_reg[2][8];
    {
        const unsigned short* ab = Wub + (long)(32 * w + rl) * D + h * 8;
        #pragma unroll
        for (int mt = 0; mt < 2; ++mt)
            #pragma unroll
            for (int s = 0; s < 8; ++s)
                a_reg[mt][s] = *(const short8*)(ab + (long)mt * 16 * D + s * 32);
    }
    f32x4 wev[2];
    wev[0] = *(const f32x4*)(we + 32 * w + h * 4);
    wev[1] = *(const f32x4*)(we + 32 * w + 16 + h * 4);

    // ---- prologue: stage tile c0 into buf 0 ----
    {
        const long m0 = (long)c0 * MT;
        float4 sv[8];
        #pragma unroll
        for (int k = 0; k < 8; ++k) {
            long n = m0 + w * 8 + k; if (n > (long)N - 1) n = (long)N - 1;
            sv[k] = *(const float4*)(feat + n * D + 4 * l);
        }
        int sr = 0; float cr = 0.f;
        if (t < MT) {
            long n = m0 + t;
            if (n < N) { sr = seg[n]; cr = cnt[n]; }
            else       { sr = seg[N - 1]; cr = 0.f; }
        }
        #pragma unroll
        for (int k = 0; k < 8; ++k) {
            int R = w * 8 + k;                       // R & 7 == k
            uint2 v = make_uint2(pack2(sv[k].x, sv[k].y), pack2(sv[k].z, sv[k].w));
            *(uint2*)&Abuf[0][R][(((l >> 1) ^ k) << 3) + (l & 1) * 4] = v;
        }
        if (t < MT) { seg_s[0][t] = sr; cnt_s[0][t] = cr; }
        __syncthreads();
    }

    int cur = 0;
    for (int tt = c0; tt < c1; ++tt, cur ^= 1) {
        const int n0  = tt * MT;
        const int nv  = min(MT, N - n0);
        const bool more = (tt + 1 < c1);
        const int* seg_t = seg_s[cur];

        // segment ids for this tile's node groups
        int sgv[4];
        #pragma unroll
        for (int nt = 0; nt < 4; ++nt) sgv[nt] = seg_t[nt * 16 + rl];

        // featv loads FIRST (oldest vmem -> counted waits later)
        f32x4 fvr[2][4];
        #pragma unroll
        for (int nt = 0; nt < 4; ++nt) {
            const float* fb = featv + (long)sgv[nt] * D + 32 * w + h * 4;
            fvr[0][nt] = *(const f32x4*)(fb);
            fvr[1][nt] = *(const f32x4*)(fb + 16);
        }
        asm volatile("" ::: "memory");

        // stage loads for tile t+1 (held in regs until after barrier 2)
        float4 sv[8];
        int sr = 0; float cr = 0.f;
        if (more) {
            const long m1 = (long)(tt + 1) * MT;
            #pragma unroll
            for (int k = 0; k < 8; ++k) {
                long n = m1 + w * 8 + k; if (n > (long)N - 1) n = (long)N - 1;
                sv[k] = *(const float4*)(feat + n * D + 4 * l);
            }
            if (t < MT) {
                long n = m1 + t;
                if (n < N) { sr = seg[n]; cr = cnt[n]; }
                else       { sr = seg[N - 1]; cr = 0.f; }
            }
        }
        asm volatile("" ::: "memory");

        // MFMA: u[j][node]; A from regs, B from bf16 swizzled LDS
        f32x4 acc[2][4];
        #pragma unroll
        for (int mt = 0; mt < 2; ++mt)
            #pragma unroll
            for (int nt = 0; nt < 4; ++nt) acc[mt][nt] = (f32x4)0.f;

        const unsigned short* Ab = &Abuf[cur][0][0];
        __builtin_amdgcn_s_setprio(1);
        #pragma unroll
        for (int s = 0; s < 8; ++s) {
            short8 bfr[4];
            #pragma unroll
            for (int nt = 0; nt < 4; ++nt) {
                int R = nt * 16 + rl;
                int gr = (s * 4 + h) ^ (rl & 7);
                bfr[nt] = *(const short8*)(Ab + R * D + gr * 8);
            }
            #pragma unroll
            for (int mt = 0; mt < 2; ++mt)
                #pragma unroll
                for (int nt = 0; nt < 4; ++nt)
                    acc[mt][nt] = __builtin_amdgcn_mfma_f32_16x16x32_bf16(a_reg[mt][s], bfr[nt], acc[mt][nt], 0, 0, 0);
        }
        __builtin_amdgcn_s_setprio(0);

        // epilogue: e partials; lane's j = 32w + 16mt + 4h + r, node = 16nt + rl
        float ep[4] = {0.f, 0.f, 0.f, 0.f};
        #pragma unroll
        for (int mt = 0; mt < 2; ++mt)
            #pragma unroll
            for (int nt = 0; nt < 4; ++nt)
                #pragma unroll
                for (int r = 0; r < 4; ++r)
                    ep[nt] += wev[mt][r] * fast_sigmoid(acc[mt][nt][r] + fvr[mt][nt][r]);
        #pragma unroll
        for (int nt = 0; nt < 4; ++nt) {
            ep[nt] += __shfl_xor(ep[nt], 16);
            ep[nt] += __shfl_xor(ep[nt], 32);
        }
        if (h == 0) {
            #pragma unroll
            for (int nt = 0; nt < 4; ++nt) e_s[w][nt * 16 + rl] = ep[nt];
        }
        asm volatile("s_waitcnt lgkmcnt(0)\ns_barrier" ::: "memory");   // barrier 1

        if (t < MT) {
            float e = 0.f;
            #pragma unroll
            for (int q = 0; q < NW; ++q) e += e_s[q][t];
            alpha_s[t] = e * cnt_s[cur][t];
        }
        asm volatile("s_waitcnt lgkmcnt(0)\ns_barrier" ::: "memory");   // barrier 2

        // write staged tile t+1 into buf^1 (counted vmcnt: atomics are newer)
        if (more) {
            #pragma unroll
            for (int k = 0; k < 8; ++k) {
                int R = w * 8 + k;
                uint2 v = make_uint2(pack2(sv[k].x, sv[k].y), pack2(sv[k].z, sv[k].w));
                *(uint2*)&Abuf[cur ^ 1][R][(((l >> 1) ^ k) << 3) + (l & 1) * 4] = v;
            }
            if (t < MT) { seg_s[cur ^ 1][t] = sr; cnt_s[cur ^ 1][t] = cr; }
        }

        // P4: segment-sum readout; thread owns dims {2p, 2p+1}, rows [16g, 16g+16)
        {
            const int p   = t & 127;
            const int gq  = t >> 7;
            const int i0  = gq * 16;
            const int i1v = min(i0 + 16, nv);
            const unsigned* Ab32 = (const unsigned*)Ab;
            if (i0 < i1v) {
                if ((i1v - i0) == 16 && seg_t[i0] == seg_t[i1v - 1]) {
                    float ca = 0.f, cb = 0.f, ca2 = 0.f, cb2 = 0.f;
                    #pragma unroll
                    for (int i2 = 0; i2 < 16; i2 += 2) {
                        int i = i0 + i2;
                        unsigned v0 = Ab32[(i + 0) * 128 + (((p >> 2) ^ ((i + 0) & 7)) << 2) + (p & 3)];
                        unsigned v1 = Ab32[(i + 1) * 128 + (((p >> 2) ^ ((i + 1) & 7)) << 2) + (p & 3)];
                        float a0 = alpha_s[i + 0], a1 = alpha_s[i + 1];
                        ca  += __uint_as_float(v0 << 16) * a0;
                        cb  += __uint_as_float(v0 & 0xffff0000u) * a0;
                        ca2 += __uint_as_float(v1 << 16) * a1;
                        cb2 += __uint_as_float(v1 & 0xffff0000u) * a1;
                    }
                    long rb = (long)seg_t[i0] * D + 2 * p;
                    atomicAdd(&rst[rb],     ca + ca2);
                    atomicAdd(&rst[rb + 1], cb + cb2);
                } else {
                    float ca = 0.f, cb = 0.f;
                    int curseg = seg_t[i0];
                    for (int i = i0; i < i1v; ++i) {
                        int sgi = seg_t[i];
                        if (sgi != curseg) {
                            long rb = (long)curseg * D + 2 * p;
                            atomicAdd(&rst[rb], ca); atomicAdd(&rst[rb + 1], cb);
                            ca = cb = 0.f; curseg = sgi;
                        }
                        unsigned v = Ab32[i * 128 + (((p >> 2) ^ (i & 7)) << 2) + (p & 3)];
                        float al = alpha_s[i];
                        ca += __uint_as_float(v << 16) * al;
                        cb += __uint_as_float(v & 0xffff0000u) * al;
                    }
                    long rb = (long)curseg * D + 2 * p;
                    atomicAdd(&rst[rb], ca); atomicAdd(&rst[rb + 1], cb);
                }
            }
        }
        asm volatile("s_waitcnt lgkmcnt(0)\ns_barrier" ::: "memory");   // barrier 3
    }
}

extern "C" void kernel_launch(void* const* d_in, const int* in_sizes, int n_in,
                              void* d_out, int out_size, void* d_ws, size_t ws_size,
                              hipStream_t stream) {
    const float* feat = (const float*)d_in[0];
    const float* cnt  = (const float*)d_in[1];
    const int*   segp = (const int*)d_in[2];
    const int*   last = (const int*)d_in[3];
    const float* Wu   = (const float*)d_in[4];
    const float* Wv   = (const float*)d_in[5];
    const float* bv   = (const float*)d_in[6];
    const float* we   = (const float*)d_in[7];
    float* rst = (float*)d_out;

    const int N    = in_sizes[1];
    const int Bseg = in_sizes[3];

    unsigned short* Wub   = (unsigned short*)d_ws;
    float*          featv = (float*)((char*)d_ws + (size_t)D * D * sizeof(unsigned short));

    const int zero_blocks = (out_size + 255) / 256;
    k_prep<<<256 + zero_blocks, 256, 0, stream>>>(Wu, Wub, rst, D * D, out_size);
    k_featv<<<(Bseg + G - 1) / G, 256, 0, stream>>>(feat, last, Wv, bv, featv, Bseg);
    k_main<<<GRID_MAIN, 512, 0, stream>>>(feat, cnt, segp, Wub, featv, we, rst, N);
}